// Round 4
// baseline (246.153 us; speedup 1.0000x reference)
//
#include <hip/hip_runtime.h>
#include <math.h>

#define C_CH 128
#define HW 128
#define KK 5
#define NW (KK*KK*C_CH + C_CH)   // 3328 weights per sample
#define RPT 16                   // output rows marched per thread

// Pure register-marching depthwise conv: no LDS, no barriers.
// 256 threads = 32 col-groups (4 cols each) x 8 row-strips (16 rows each).
// Each thread keeps a 5-row x 8-col input window in VGPRs (slot rotation
// with compile-time indices via full unroll) and streams down its strip.
__global__ __launch_bounds__(256, 6) void hyperconv_dw_silu(
    const float* __restrict__ inp, const float* __restrict__ wts,
    float* __restrict__ out)
{
    const int tid = threadIdx.x;
    const int c   = blockIdx.x;   // channel (block-uniform -> scalar weights)
    const int b   = blockIdx.y;   // batch

    const float* wt = wts + (size_t)b * NW;
    float wk[25];
#pragma unroll
    for (int j = 0; j < 25; ++j) wk[j] = wt[c * 25 + j];
    const float bias = wt[KK * KK * C_CH + c];

    const float* plane  = inp + ((size_t)(b * C_CH + c)) * (HW * HW);
    float*       oplane = out + ((size_t)(b * C_CH + c)) * (HW * HW);

    const int colg = tid & 31;        // cols 4*colg .. 4*colg+3
    const int rowg = tid >> 5;        // strip: rows rowg*16 .. rowg*16+15
    const int r0   = rowg * RPT;
    const int xb   = colg * 4;
    const int lcb  = (colg == 0)  ? 0   : (xb - 4);   // aligned left read
    const int rcb  = (colg == 31) ? 120 : (xb + 4);   // aligned right read

    float w[5][8];   // 5-row sliding window, cols xb-2 .. xb+5

    // load global input row ir into an 8-float window row (zeros outside image)
    auto load_row = [&](int ir, float* wr) {
        const int irc = (ir < 0) ? 0 : ((ir > 127) ? 127 : ir);
        const float* row = plane + irc * HW;
        const float4 xl = *(const float4*)(row + lcb);
        const float4 xm = *(const float4*)(row + xb);
        const float4 xr = *(const float4*)(row + rcb);
        const bool vz = (ir < 0) | (ir > 127);
        const bool lz = vz | (colg == 0);
        const bool rz = vz | (colg == 31);
        wr[0] = lz ? 0.f : xl.z;
        wr[1] = lz ? 0.f : xl.w;
        wr[2] = vz ? 0.f : xm.x;
        wr[3] = vz ? 0.f : xm.y;
        wr[4] = vz ? 0.f : xm.z;
        wr[5] = vz ? 0.f : xm.w;
        wr[6] = rz ? 0.f : xr.x;
        wr[7] = rz ? 0.f : xr.y;
    };

    // prologue: rows r0-2 .. r0+1 -> slots 0..3
#pragma unroll
    for (int i = 0; i < 4; ++i) load_row(r0 - 2 + i, w[i]);

    // march: step s emits output row r0+s.
    // slot invariant: input row (r0+s-2+kh) lives in slot (s+kh)%5;
    // step s loads row r0+s+2 into slot (s+4)%5 (overwrites the retiring row).
#pragma unroll
    for (int s = 0; s < RPT; ++s) {
        load_row(r0 + s + 2, w[(s + 4) % 5]);

        float acc[4] = {bias, bias, bias, bias};
#pragma unroll
        for (int kh = 0; kh < 5; ++kh) {
            const float* wr = w[(s + kh) % 5];   // compile-time after unroll
#pragma unroll
            for (int oc = 0; oc < 4; ++oc)
#pragma unroll
                for (int kw = 0; kw < 5; ++kw)
                    acc[oc] = fmaf(wk[kh * 5 + kw], wr[oc + kw], acc[oc]);
        }

        float4 o;
        o.x = acc[0] * __builtin_amdgcn_rcpf(1.0f + __expf(-acc[0]));
        o.y = acc[1] * __builtin_amdgcn_rcpf(1.0f + __expf(-acc[1]));
        o.z = acc[2] * __builtin_amdgcn_rcpf(1.0f + __expf(-acc[2]));
        o.w = acc[3] * __builtin_amdgcn_rcpf(1.0f + __expf(-acc[3]));
        *(float4*)(oplane + (size_t)(r0 + s) * HW + xb) = o;
    }
}

extern "C" void kernel_launch(void* const* d_in, const int* in_sizes, int n_in,
                              void* d_out, int out_size, void* d_ws, size_t ws_size,
                              hipStream_t stream) {
    const float* inp = (const float*)d_in[0];
    const float* wts = (const float*)d_in[1];
    float* out = (float*)d_out;

    const int batch = in_sizes[1] / NW;   // 16
    dim3 grid(C_CH, batch);               // one block per (channel, batch) plane
    hyperconv_dw_silu<<<grid, 256, 0, stream>>>(inp, wts, out);
}

// Round 6
// 245.870 us; speedup vs baseline: 1.0012x; 1.0012x over previous
//
#include <hip/hip_runtime.h>
#include <math.h>

#define C_CH 128
#define HW 128
#define KK 5
#define NW (KK*KK*C_CH + C_CH)   // 3328 weights per sample
#define TR 8                     // output rows per thread
#define IR (TR + 4)              // input rows walked per thread (with +/-2 halo)

typedef float __attribute__((ext_vector_type(4))) floatx4;  // native vector:
// __builtin_nontemporal_store rejects HIP_vector_type<float,4> (round-5 error)

// Streaming depthwise conv, no LDS, no barriers, immediate-consumption form:
// each thread owns an 8-row x 4-col output tile (acc[8][4], statically
// indexed), walks its 12 input rows ONCE each (3 aligned float4 loads/row),
// and FMAs each input row into the <=5 accumulator rows it feeds. No
// rotating window, no pointers into arrays -> nothing for the register
// allocator to demote (round-4 lesson: VGPR_Count=36 < window size proved
// the %5-pointer window was demoted and loads were rematerialized ~5x).
__global__ __launch_bounds__(256, 4) void hyperconv_dw_silu(
    const float* __restrict__ inp, const float* __restrict__ wts,
    float* __restrict__ out)
{
    const int tid  = threadIdx.x;
    const int half = blockIdx.x;   // 0: rows 0-63, 1: rows 64-127
    const int c    = blockIdx.y;   // channel (block-uniform -> scalar weights)
    const int b    = blockIdx.z;   // batch

    const float* wt = wts + (size_t)b * NW;
    float wk[25];
#pragma unroll
    for (int j = 0; j < 25; ++j) wk[j] = wt[c * 25 + j];
    const float bias = wt[KK * KK * C_CH + c];

    const float* plane  = inp + ((size_t)(b * C_CH + c)) * (HW * HW);
    float*       oplane = out + ((size_t)(b * C_CH + c)) * (HW * HW);

    const int colg = tid & 31;            // cols 4*colg .. 4*colg+3
    const int rowg = tid >> 5;            // 8 row-strips of 8 rows
    const int r0   = half * 64 + rowg * TR;
    const int xb   = colg * 4;
    const int lcb  = (colg == 0)  ? 0   : (xb - 4);   // aligned left window read
    const int rcb  = (colg == 31) ? 120 : (xb + 4);   // aligned right window read

    float acc[TR][4];
#pragma unroll
    for (int i = 0; i < TR; ++i)
#pragma unroll
        for (int j = 0; j < 4; ++j) acc[i][j] = bias;

#pragma unroll
    for (int r = 0; r < IR; ++r) {
        const int ir  = r0 - 2 + r;                    // global input row
        const int irc = (ir < 0) ? 0 : ((ir > 127) ? 127 : ir);
        const float* row = plane + irc * HW;
        const float4 xl = *(const float4*)(row + lcb);
        const float4 xm = *(const float4*)(row + xb);
        const float4 xr = *(const float4*)(row + rcb);
        const bool vz = (ir < 0) | (ir > 127);
        const bool lz = vz | (colg == 0);
        const bool rz = vz | (colg == 31);

        float x[8];                                    // cols xb-2 .. xb+5
        x[0] = lz ? 0.f : xl.z;
        x[1] = lz ? 0.f : xl.w;
        x[2] = vz ? 0.f : xm.x;
        x[3] = vz ? 0.f : xm.y;
        x[4] = vz ? 0.f : xm.z;
        x[5] = vz ? 0.f : xm.w;
        x[6] = rz ? 0.f : xr.x;
        x[7] = rz ? 0.f : xr.y;

        // input row ir feeds output rows orow with kh = r - orow in [0,4]
#pragma unroll
        for (int orow = 0; orow < TR; ++orow) {
            const int kh = r - orow;
            if (kh < 0 || kh > 4) continue;            // compile-time prune
#pragma unroll
            for (int oc = 0; oc < 4; ++oc)
#pragma unroll
                for (int kw = 0; kw < 5; ++kw)
                    acc[orow][oc] = fmaf(wk[kh * 5 + kw], x[oc + kw], acc[orow][oc]);
        }
    }

    // epilogue: fast SiLU + non-temporal float4 stores (output never re-read;
    // keep L2/L3 capacity for input halo re-reads)
#pragma unroll
    for (int orow = 0; orow < TR; ++orow) {
        const float v0 = acc[orow][0], v1 = acc[orow][1];
        const float v2 = acc[orow][2], v3 = acc[orow][3];
        floatx4 o;
        o.x = v0 * __builtin_amdgcn_rcpf(1.0f + __expf(-v0));
        o.y = v1 * __builtin_amdgcn_rcpf(1.0f + __expf(-v1));
        o.z = v2 * __builtin_amdgcn_rcpf(1.0f + __expf(-v2));
        o.w = v3 * __builtin_amdgcn_rcpf(1.0f + __expf(-v3));
        __builtin_nontemporal_store(o, (floatx4*)(oplane + (size_t)(r0 + orow) * HW + xb));
    }
}

extern "C" void kernel_launch(void* const* d_in, const int* in_sizes, int n_in,
                              void* d_out, int out_size, void* d_ws, size_t ws_size,
                              hipStream_t stream) {
    const float* inp = (const float*)d_in[0];
    const float* wts = (const float*)d_in[1];
    float* out = (float*)d_out;

    const int batch = in_sizes[1] / NW;   // 16
    dim3 grid(2, C_CH, batch);            // 2 half-plane blocks per (c,b) plane
    hyperconv_dw_silu<<<grid, 256, 0, stream>>>(inp, wts, out);
}